// Round 3
// baseline (257.291 us; speedup 1.0000x reference)
//
#include <hip/hip_runtime.h>

#define SLEN 2048
#define NHEADS 16
#define HDIM 128

typedef __attribute__((ext_vector_type(8))) short bf16x8;
typedef __attribute__((ext_vector_type(4))) float f32x4;
typedef __attribute__((ext_vector_type(16))) float f32x16;

__device__ __forceinline__ unsigned short f2bf(float f) {
  union { float f; unsigned u; } v; v.f = f;
  unsigned r = v.u + 0x7FFFu + ((v.u >> 16) & 1u);
  return (unsigned short)(r >> 16);
}

__device__ __forceinline__ unsigned pkbf(float a, float b) {
  unsigned r;
  asm("v_cvt_pk_bf16_f32 %0, %1, %2" : "=v"(r) : "v"(a), "v"(b));
  return r;
}

__device__ __forceinline__ void gload16(const void* g, void* l) {
  __builtin_amdgcn_global_load_lds(
      (const __attribute__((address_space(1))) unsigned int*)g,
      (__attribute__((address_space(3))) unsigned int*)l, 16, 0, 0);
}

// ---------------- f32 -> bf16 conversion (8 elems/thread) ----------------
__global__ __launch_bounds__(256) void cvt_f32_bf16(const float* __restrict__ in,
                                                    unsigned short* __restrict__ out,
                                                    int n8) {
  int i = blockIdx.x * 256 + threadIdx.x;
  if (i >= n8) return;
  const float4* p = reinterpret_cast<const float4*>(in) + (size_t)i * 2;
  float4 a = p[0], b = p[1];
  uint4 o;
  o.x = (unsigned)f2bf(a.x) | ((unsigned)f2bf(a.y) << 16);
  o.y = (unsigned)f2bf(a.z) | ((unsigned)f2bf(a.w) << 16);
  o.z = (unsigned)f2bf(b.x) | ((unsigned)f2bf(b.y) << 16);
  o.w = (unsigned)f2bf(b.z) | ((unsigned)f2bf(b.w) << 16);
  reinterpret_cast<uint4*>(out)[i] = o;
}

// ---------------- C = A[M,K] * B[N,K]^T, bf16 in, f32 acc ----------------
template <bool OUT_F32>
__global__ __launch_bounds__(256) void gemm_bt(const unsigned short* __restrict__ A,
                                               const unsigned short* __restrict__ B,
                                               void* __restrict__ Cv,
                                               int M, int N, int K) {
  __shared__ unsigned short As[128 * 32];
  __shared__ unsigned short Bs[128 * 32];
  const int tid = threadIdx.x;
  const int lane = tid & 63, wid = tid >> 6;
  const int g = lane >> 4, q = lane & 15;
  const int nbx = N >> 7;
  const int bx = blockIdx.x % nbx, by = blockIdx.x / nbx;
  const int tM = by << 7, tN = bx << 7;
  const int wm = (wid >> 1) * 64, wn = (wid & 1) * 64;

  f32x4 acc[4][4] = {};

  const int o0 = tid * 16;
  const int r0 = o0 >> 6, c0 = (o0 & 63) >> 1;
  const int r1 = r0 + 64;
  const unsigned short* gA0 = A + (size_t)(tM + r0) * K + c0;
  const unsigned short* gA1 = A + (size_t)(tM + r1) * K + c0;
  const unsigned short* gB0 = B + (size_t)(tN + r0) * K + c0;
  const unsigned short* gB1 = B + (size_t)(tN + r1) * K + c0;
  char* lA = (char*)As;
  char* lB = (char*)Bs;
  const int wo = wid * 1024;

  for (int kt = 0; kt < K; kt += 32) {
    gload16(gA0, lA + wo);
    gload16(gA1, lA + 4096 + wo);
    gload16(gB0, lB + wo);
    gload16(gB1, lB + 4096 + wo);
    gA0 += 32; gA1 += 32; gB0 += 32; gB1 += 32;
    __syncthreads();
    bf16x8 af[4], bfr[4];
#pragma unroll
    for (int i = 0; i < 4; ++i)
      af[i] = *(const bf16x8*)&As[(wm + i * 16 + q) * 32 + g * 8];
#pragma unroll
    for (int j = 0; j < 4; ++j)
      bfr[j] = *(const bf16x8*)&Bs[(wn + j * 16 + q) * 32 + g * 8];
#pragma unroll
    for (int i = 0; i < 4; ++i)
#pragma unroll
      for (int j = 0; j < 4; ++j)
        acc[i][j] = __builtin_amdgcn_mfma_f32_16x16x32_bf16(af[i], bfr[j], acc[i][j], 0, 0, 0);
    __syncthreads();
  }

  if constexpr (OUT_F32) {
    float* C = (float*)Cv;
#pragma unroll
    for (int i = 0; i < 4; ++i)
#pragma unroll
      for (int j = 0; j < 4; ++j)
#pragma unroll
        for (int r = 0; r < 4; ++r)
          C[(size_t)(tM + wm + i * 16 + g * 4 + r) * N + (tN + wn + j * 16 + q)] =
              acc[i][j][r];
  } else {
    unsigned short* C = (unsigned short*)Cv;
#pragma unroll
    for (int i = 0; i < 4; ++i)
#pragma unroll
      for (int j = 0; j < 4; ++j)
#pragma unroll
        for (int r = 0; r < 4; ++r)
          C[(size_t)(tM + wm + i * 16 + g * 4 + r) * N + (tN + wn + j * 16 + q)] =
              f2bf(acc[i][j][r]);
  }
}

// ---------------- causal flash attention, 32x32 MFMA ----------------
// Grid 512: pi = bid>>5 (qt = 15-pi, heavy first), bh = bid&31.
// Block: 4 waves x 32 q-rows = 128-row q-tile; KVBLK = 64.
// Swapped QK^T (St = K*Q^T) -> P lane-local in q; in-register softmax + pack.
// K [s][2048] and VT [hd][s] staged to LDS via global_load_lds, double-buffered,
// XOR-swizzled (chunk16 ^= row&7 on pre-swizzled source AND on ds_read addr).
// One raw barrier + exact vmcnt(0) per tile; no ds_writes anywhere.
__global__ __launch_bounds__(256, 2) void mla_attn(const unsigned short* __restrict__ Q,
                                                   const unsigned short* __restrict__ K,
                                                   const unsigned short* __restrict__ VT,
                                                   unsigned short* __restrict__ AO) {
  __shared__ unsigned short Ks[2][64 * 128];   // [kv][d], swizzled
  __shared__ unsigned short Vs[2][128 * 64];   // [d][kv], swizzled

  const int tid = threadIdx.x, lane = tid & 63, w = tid >> 6;
  const int q5 = lane & 31, half = lane >> 5, q7 = lane & 7;
  const int pi = blockIdx.x >> 5, bh = blockIdx.x & 31;
  const int head = bh & 15, b = bh >> 4;
  const int qt = 15 - pi;
  const int nt = 2 * qt + 2;
  const int myq = qt * 128 + w * 32 + q5;

  const unsigned short* Kbase = K + (size_t)(b * 2048) * 2048 + head * 128;
  const unsigned short* Vbase = VT + (size_t)(b * 2048 + head * 128) * 2048;
  const unsigned short* Qrow = Q + (size_t)(b * 2048 + myq) * 2048 + head * 128;

  // staging source coords (pre-swizzled)
  const int r0 = tid >> 4, c0 = tid & 15;               // K: 16 chunks/row
  const unsigned short* kS = Kbase + (size_t)r0 * 2048 + ((c0 ^ (r0 & 7)) << 3);
  const int d0 = tid >> 3, c3 = tid & 7;                // VT: 8 chunks/row
  const unsigned short* vS = Vbase + (size_t)d0 * 2048 + ((c3 ^ (d0 & 7)) << 3);

  // hoist Q B-frags: col=q5, k = ks*16 + half*8 + j
  bf16x8 qf[8];
#pragma unroll
  for (int ks = 0; ks < 8; ++ks)
    qf[ks] = *(const bf16x8*)((const char*)Qrow + ks * 32 + half * 16);

  // stage tile 0
  {
    unsigned short* kd = &Ks[0][0] + tid * 8;
    unsigned short* vd = &Vs[0][0] + tid * 8;
#pragma unroll
    for (int s = 0; s < 4; ++s) {
      gload16(kS + (size_t)s * 16 * 2048, kd + s * 2048);
      gload16(vS + (size_t)s * 32 * 2048, vd + s * 2048);
    }
  }

  float m2 = -1e30f, l = 0.f;
  f32x16 o[4];
#pragma unroll
  for (int i = 0; i < 16; ++i) { o[0][i] = 0.f; o[1][i] = 0.f; o[2][i] = 0.f; o[3][i] = 0.f; }

  const float sc_f = 0.08838834764831845f;  // 1/sqrt(128)
  const int arow0 = q5 * 256;   // K LDS row byte base (+ m*8192)
  const int vrow0 = q5 * 128;   // VT LDS row byte base (+ nf*4096)

  for (int kt = 0; kt < nt; ++kt) {
    const int cur = kt & 1;
    asm volatile("s_waitcnt vmcnt(0)" ::: "memory");  // tile kt staged (issued 1 iter ago)
    __builtin_amdgcn_s_barrier();

    if (kt + 1 < nt) {  // stage tile kt+1 into the other buffer
      const int kvb2 = (kt + 1) * 64;
      unsigned short* kd = &Ks[cur ^ 1][0] + tid * 8;
      unsigned short* vd = &Vs[cur ^ 1][0] + tid * 8;
      const unsigned short* ks2 = kS + (size_t)kvb2 * 2048;
      const unsigned short* vs2 = vS + kvb2;
#pragma unroll
      for (int s = 0; s < 4; ++s) {
        gload16(ks2 + (size_t)s * 16 * 2048, kd + s * 2048);
        gload16(vs2 + (size_t)s * 32 * 2048, vd + s * 2048);
      }
    }

    // ---- QK^T: St[kv][q], A = K rows (LDS), B = Q (regs) ----
    f32x16 st[2];
#pragma unroll
    for (int i = 0; i < 16; ++i) { st[0][i] = 0.f; st[1][i] = 0.f; }
    const char* kb = (const char*)&Ks[cur][0];
#pragma unroll
    for (int ks = 0; ks < 8; ++ks) {
      const int cd = ks * 2 + half;
#pragma unroll
      for (int m = 0; m < 2; ++m) {
        bf16x8 kf = *(const bf16x8*)(kb + arow0 + m * 8192 + ((cd ^ q7) << 4));
        st[m] = __builtin_amdgcn_mfma_f32_32x32x16_bf16(kf, qf[ks], st[m], 0, 0, 0);
      }
    }

    // ---- softmax (lane owns q-col q5; 32 kv values, partner has the rest) ----
    float t[32];
    const int kvb = kt * 64;
    const bool needmask = (kvb + 63 > qt * 128 + w * 32);
#pragma unroll
    for (int m = 0; m < 2; ++m)
#pragma unroll
      for (int r = 0; r < 16; ++r) {
        float s = st[m][r] * sc_f;
        if (needmask) {
          const int kvloc = m * 32 + (r & 3) + 8 * (r >> 2) + 4 * half;
          s = (kvb + kvloc <= myq) ? s : -3e38f;
        }
        t[m * 16 + r] = s;
      }
    float mx = t[0];
#pragma unroll
    for (int i = 1; i < 32; ++i) mx = fmaxf(mx, t[i]);
    mx = fmaxf(mx, __shfl_xor(mx, 32));

    if (!__all(mx <= m2 + 8.f)) {  // defer-max (T13)
      const float mnew = fmaxf(m2, mx);
      const float rsc = __expf(m2 - mnew);
      m2 = mnew; l *= rsc;
#pragma unroll
      for (int r = 0; r < 16; ++r) {
        const int rowv = (r & 3) + 8 * (r >> 2) + 4 * half;
        const float f = __shfl(rsc, rowv);
        o[0][r] *= f; o[1][r] *= f; o[2][r] *= f; o[3][r] *= f;
      }
    }

    float ts = 0.f;
#pragma unroll
    for (int i = 0; i < 32; ++i) { t[i] = __expf(t[i] - m2); ts += t[i]; }
    ts += __shfl_xor(ts, 32);
    l += ts;

    // ---- pack P to bf16 word pairs: wpk[m][r4][j] = (p[r2=2j], p[r2=2j+1]) ----
    unsigned wpk[2][4][2];
#pragma unroll
    for (int m = 0; m < 2; ++m)
#pragma unroll
      for (int r4 = 0; r4 < 4; ++r4) {
        wpk[m][r4][0] = pkbf(t[m * 16 + r4 * 4 + 0], t[m * 16 + r4 * 4 + 1]);
        wpk[m][r4][1] = pkbf(t[m * 16 + r4 * 4 + 2], t[m * 16 + r4 * 4 + 3]);
      }

    // ---- PV: A-frag kv-run = ks*16 + half*8; exchange halves via shfl_xor(32) ----
    const char* vb = (const char*)&Vs[cur][0];
#pragma unroll
    for (int ks = 0; ks < 4; ++ks) {
      const int m = ks >> 1, i = ks & 1;
      const unsigned s0 = half ? wpk[m][2 * i][0] : wpk[m][2 * i + 1][0];
      const unsigned s1 = half ? wpk[m][2 * i][1] : wpk[m][2 * i + 1][1];
      const unsigned rv0 = (unsigned)__shfl_xor((int)s0, 32);
      const unsigned rv1 = (unsigned)__shfl_xor((int)s1, 32);
      const unsigned ow0 = half ? wpk[m][2 * i + 1][0] : wpk[m][2 * i][0];
      const unsigned ow1 = half ? wpk[m][2 * i + 1][1] : wpk[m][2 * i][1];
      union { unsigned u[4]; bf16x8 v; } fr;
      fr.u[0] = half ? rv0 : ow0;
      fr.u[1] = half ? rv1 : ow1;
      fr.u[2] = half ? ow0 : rv0;
      fr.u[3] = half ? ow1 : rv1;
      const int cd = ks * 2 + half;
#pragma unroll
      for (int nf = 0; nf < 4; ++nf) {
        bf16x8 vf = *(const bf16x8*)(vb + vrow0 + nf * 4096 + ((cd ^ q7) << 4));
        o[nf] = __builtin_amdgcn_mfma_f32_32x32x16_bf16(fr.v, vf, o[nf], 0, 0, 0);
      }
    }
  }

  // ---- epilogue ----
  const float linv = 1.0f / l;
  unsigned short* aob = AO + (size_t)(b * 2048) * 2048 + head * 128;
#pragma unroll
  for (int r = 0; r < 16; ++r) {
    const int rowv = (r & 3) + 8 * (r >> 2) + 4 * half;
    const float f = __shfl(linv, rowv);
    const size_t qa = (size_t)(qt * 128 + w * 32 + rowv);
#pragma unroll
    for (int nf = 0; nf < 4; ++nf)
      aob[qa * 2048 + nf * 32 + q5] = f2bf(o[nf][r] * f);
  }
}

extern "C" void kernel_launch(void* const* d_in, const int* in_sizes, int n_in,
                              void* d_out, int out_size, void* d_ws, size_t ws_size,
                              hipStream_t stream) {
  const float* q    = (const float*)d_in[0];
  const float* lat  = (const float*)d_in[1];
  const float* Wq   = (const float*)d_in[2];
  const float* Wkv  = (const float*)d_in[3];
  const float* Wout = (const float*)d_in[4];

  char* ws = (char*)d_ws;
  unsigned short* qbf   = (unsigned short*)(ws);             // 16 MiB (reused as aobf)
  unsigned short* aobf  = (unsigned short*)(ws);
  unsigned short* Wqbf  = (unsigned short*)(ws + 16777216);  // 8 MiB
  unsigned short* latbf = (unsigned short*)(ws + 25165824);  // 4 MiB
  unsigned short* Wkvbf = (unsigned short*)(ws + 29360128);  // 4 MiB
  unsigned short* Wobf  = (unsigned short*)(ws + 33554432);  // 8 MiB
  unsigned short* qpbf  = (unsigned short*)(ws + 41943040);  // 16 MiB [4096,2048]
  unsigned short* Kbf   = (unsigned short*)(ws + 58720256);  // 16 MiB [4096,2048]
  unsigned short* VTbf  = (unsigned short*)(ws + 75497472);  // 16 MiB [2][2048 hd][2048 s]
  unsigned short* Wvbf  = Wkvbf + (size_t)2048 * 512;

  cvt_f32_bf16<<<4096, 256, 0, stream>>>(q, qbf, 1048576);
  cvt_f32_bf16<<<2048, 256, 0, stream>>>(Wq, Wqbf, 524288);
  cvt_f32_bf16<<<1024, 256, 0, stream>>>(lat, latbf, 262144);
  cvt_f32_bf16<<<1024, 256, 0, stream>>>(Wkv, Wkvbf, 262144);
  cvt_f32_bf16<<<2048, 256, 0, stream>>>(Wout, Wobf, 524288);

  // qp = q * Wq^T
  gemm_bt<false><<<512, 256, 0, stream>>>(qbf, Wqbf, qpbf, 4096, 2048, 2048);
  // K = latent * Wk^T   [4096,2048]
  gemm_bt<false><<<512, 256, 0, stream>>>(latbf, Wkvbf, Kbf, 4096, 2048, 512);
  // V^T = Wv * latent^T per batch: [2048 hd, 2048 s]
  gemm_bt<false><<<256, 256, 0, stream>>>(Wvbf, latbf, VTbf, 2048, 2048, 512);
  gemm_bt<false><<<256, 256, 0, stream>>>(Wvbf, latbf + (size_t)2048 * 512,
                                          VTbf + (size_t)2048 * 2048, 2048, 2048, 512);
  // attention
  mla_attn<<<512, 256, 0, stream>>>(qpbf, Kbf, VTbf, aobf);
  // out = ao * Wout^T -> f32
  gemm_bt<true><<<512, 256, 0, stream>>>(aobf, Wobf, (float*)d_out, 4096, 2048, 2048);
}